// Round 3
// baseline (123.091 us; speedup 1.0000x reference)
//
#include <hip/hip_runtime.h>
#include <math.h>

namespace {

typedef float f32x4 __attribute__((ext_vector_type(4)));

constexpr int kPts   = 2 * 256 * 256;   // 131072 points
constexpr int kPlane = kPts;            // stride between (row,col) planes
constexpr int kHid   = 64;
constexpr int kPath  = 384;
constexpr int kG     = 8;               // uv-slices (gridDim.y)
constexpr int kUvPer = 64 / kG;         // 8 uv pairs per block

// ws layout: W2T[384*64] floats | V[384] floats | flag (unsigned)
constexpr size_t kWsV    = (size_t)kPath * kHid;   // float index
constexpr size_t kWsFlag = kWsV + kPath;           // float index
constexpr size_t kWsNeedBytes = (kWsFlag + 1) * sizeof(float);

__global__ void prep_kernel(const float* __restrict__ W1,
                            const float* __restrict__ b1,
                            const float* __restrict__ W2,
                            float* __restrict__ W2T,
                            float* __restrict__ V,
                            unsigned* __restrict__ flag)
{
    int t = blockIdx.x * blockDim.x + threadIdx.x;
    if (t < kPath * kHid) {
        int p = t >> 6, i = t & 63;
        W2T[t] = W2[i * kPath + p];
    }
    if (t < kPath) {
        float acc = 0.f;
        for (int i = 0; i < kHid; ++i)
            acc += fmaxf(W1[i], 0.f) * W2[i * kPath + t];
        V[t] = acc;
    }
    if (t == 0) {
        unsigned f = 1u;
        for (int i = 0; i < kHid; ++i)
            if (b1[i] != 0.f) f = 0u;
        *flag = f;
    }
}

template <bool USE_WS>
__global__ __launch_bounds__(256)
void se3_kernel(const float* __restrict__ dm,
                const float* __restrict__ W1,
                const float* __restrict__ b1,
                const float* __restrict__ W2,    // (64,384) original
                const float* __restrict__ b2,
                const float* __restrict__ Q00,   // (1,1,1)
                const float* __restrict__ Q01,   // (1,3,3)
                const float* __restrict__ Q10,   // (3,1,3)
                const float* __restrict__ Q11,   // (3,3,9)
                const float* __restrict__ W2T,   // (384,64) if USE_WS
                const float* __restrict__ V,     // (384)    if USE_WS
                const unsigned* __restrict__ flag,
                float* __restrict__ out)
{
    const int g   = blockIdx.x * blockDim.x + threadIdx.x;  // point-group (4 pts)
    const int uv0 = blockIdx.y * kUvPer;

    // ---- load 4 points' xyz (3 x dwordx4) ----
    const f32x4* dmv = reinterpret_cast<const f32x4*>(dm) + 3 * (size_t)g;
    f32x4 f0 = dmv[0], f1 = dmv[1], f2 = dmv[2];
    float px[4] = { f0.x, f0.w, f1.z, f2.y };
    float py[4] = { f0.y, f1.x, f1.w, f2.z };
    float pz[4] = { f0.z, f1.y, f2.x, f2.w };

    float r[4], ux[4], uy[4], uz[4];
#pragma unroll
    for (int p = 0; p < 4; ++p) {
        r[p] = sqrtf(px[p] * px[p] + py[p] * py[p] + pz[p] * pz[p]);
        float inv = 1.0f / fmaxf(r[p], 1e-12f);
        ux[p] = px[p] * inv; uy[p] = py[p] * inv; uz[p] = pz[p] * inv;
    }

    const float Y0 = 0.28209479177387814f;
    const float c1 = 0.4886025119029199f;
    float Y10[4], Y11[4], Y12[4], Y2[5][4];
#pragma unroll
    for (int p = 0; p < 4; ++p) {
        Y10[p] = c1 * uy[p];
        Y11[p] = c1 * uz[p];
        Y12[p] = c1 * ux[p];
        Y2[0][p] = 1.0925484305920792f * ux[p] * uy[p];
        Y2[1][p] = 1.0925484305920792f * uy[p] * uz[p];
        Y2[2][p] = 0.31539156525252005f * (3.f * uz[p] * uz[p] - 1.f);
        Y2[3][p] = 1.0925484305920792f * ux[p] * uz[p];
        Y2[4][p] = 0.5462742152960396f * (ux[p] * ux[p] - uy[p] * uy[p]);
    }

    // norm = sqrt(2*l_in+1)*sqrt(4*pi)/sqrt(num); num0=4096, num1=8192
    constexpr float kS4pi = 3.5449077018110318f;
    constexpr float kSq3  = 1.7320508075688772f;
    const float n00 = kS4pi / 64.f;
    const float n01 = kSq3 * kS4pi / 64.f;
    const float n10 = kS4pi / 90.50966799187809f;
    const float n11 = kSq3 * kS4pi / 90.50966799187809f;

    // point-independent factors (scalar)
    const float s00 = n00 * Q00[0] * Y0;
    float G0[9];
#pragma unroll
    for (int e = 0; e < 9; ++e) G0[e] = n11 * Q11[e * 9 + 0] * Y0;

    // per-point geometry factors
    float g01[3][4], g10[3][4], G1[9][4], G2[9][4];
#pragma unroll
    for (int jc = 0; jc < 3; ++jc) {
        float q0 = Q01[jc * 3 + 0], q1 = Q01[jc * 3 + 1], q2 = Q01[jc * 3 + 2];
#pragma unroll
        for (int p = 0; p < 4; ++p)
            g01[jc][p] = n01 * (q0 * Y10[p] + q1 * Y11[p] + q2 * Y12[p]);
    }
#pragma unroll
    for (int ir = 0; ir < 3; ++ir) {
        float q0 = Q10[ir * 3 + 0], q1 = Q10[ir * 3 + 1], q2 = Q10[ir * 3 + 2];
#pragma unroll
        for (int p = 0; p < 4; ++p)
            g10[ir][p] = n10 * (q0 * Y10[p] + q1 * Y11[p] + q2 * Y12[p]);
    }
#pragma unroll
    for (int e = 0; e < 9; ++e) {
        const float* q = Q11 + e * 9;
        float q1 = q[1], q2 = q[2], q3 = q[3];
        float q4 = q[4], q5 = q[5], q6 = q[6], q7 = q[7], q8 = q[8];
#pragma unroll
        for (int p = 0; p < 4; ++p) {
            G1[e][p] = n11 * (q1 * Y10[p] + q2 * Y11[p] + q3 * Y12[p]);
            G2[e][p] = n11 * (q4 * Y2[0][p] + q5 * Y2[1][p] + q6 * Y2[2][p] +
                              q7 * Y2[3][p] + q8 * Y2[4][p]);
        }
    }

    float* __restrict__ obase = out + 4 * (size_t)g;
    auto stf = [&](int row, const float* v4) {
        f32x4 q;
        q.x = v4[0]; q.y = v4[1]; q.z = v4[2]; q.w = v4[3];
        __builtin_nontemporal_store(q,
            reinterpret_cast<f32x4*>(obase + (size_t)row * kPlane));
    };

    auto emit = [&](int uv, const float* w00, const float* w01,
                    const float* w10, const float* w110,
                    const float* w111, const float* w112) {
        const int u = uv >> 3, v = uv & 7;
        const int rowu = u * 32;
        float tmp[4];
#pragma unroll
        for (int p = 0; p < 4; ++p) tmp[p] = s00 * w00[p];
        stf(rowu + v, tmp);
#pragma unroll
        for (int jc = 0; jc < 3; ++jc) {
#pragma unroll
            for (int p = 0; p < 4; ++p) tmp[p] = g01[jc][p] * w01[p];
            stf(rowu + 8 + v * 3 + jc, tmp);
        }
#pragma unroll
        for (int ir = 0; ir < 3; ++ir) {
            const int rowb = (8 + u * 3 + ir) * 32;
#pragma unroll
            for (int p = 0; p < 4; ++p) tmp[p] = g10[ir][p] * w10[p];
            stf(rowb + v, tmp);
#pragma unroll
            for (int jc = 0; jc < 3; ++jc) {
                const int e = ir * 3 + jc;
#pragma unroll
                for (int p = 0; p < 4; ++p)
                    tmp[p] = fmaf(G0[e], w110[p],
                              fmaf(G1[e][p], w111[p], G2[e][p] * w112[p]));
                stf(rowb + 8 + v * 3 + jc, tmp);
            }
        }
    };

    bool fast = false;
    if constexpr (USE_WS) fast = (*flag != 0u);

    if (USE_WS && fast) {
        // b1 == 0 and r >= 0  =>  weights[p] = r * V[p] + b2[p] exactly
#pragma unroll 1
        for (int t = 0; t < kUvPer; ++t) {
            const int uv = uv0 + t;
            float v00 = V[uv],            c00 = b2[uv];
            float v01 = V[64 + uv],       c01 = b2[64 + uv];
            float v10 = V[128 + uv],      c10 = b2[128 + uv];
            float v50 = V[192 + 3 * uv],  c50 = b2[192 + 3 * uv];
            float v51 = V[193 + 3 * uv],  c51 = b2[193 + 3 * uv];
            float v52 = V[194 + 3 * uv],  c52 = b2[194 + 3 * uv];
            float w00[4], w01[4], w10[4], w110[4], w111[4], w112[4];
#pragma unroll
            for (int p = 0; p < 4; ++p) {
                w00[p]  = fmaf(r[p], v00, c00);
                w01[p]  = fmaf(r[p], v01, c01);
                w10[p]  = fmaf(r[p], v10, c10);
                w110[p] = fmaf(r[p], v50, c50);
                w111[p] = fmaf(r[p], v51, c51);
                w112[p] = fmaf(r[p], v52, c52);
            }
            emit(uv, w00, w01, w10, w110, w111, w112);
        }
    } else {
        // general path: honest per-point hidden layer, register-light
        // (recompute h inside the i-loop; slow but only runs when b1 != 0)
#pragma unroll 1
        for (int t = 0; t < kUvPer; ++t) {
            const int uv = uv0 + t;
            float a00[4], a01[4], a10[4], a110[4], a111[4], a112[4];
#pragma unroll
            for (int p = 0; p < 4; ++p) {
                a00[p]  = b2[uv];
                a01[p]  = b2[64 + uv];
                a10[p]  = b2[128 + uv];
                a110[p] = b2[192 + 3 * uv];
                a111[p] = b2[193 + 3 * uv];
                a112[p] = b2[194 + 3 * uv];
            }
#pragma unroll 1
            for (int i = 0; i < kHid; ++i) {
                float w1i = W1[i], b1i = b1[i];
                float c00, c01, c10, c50, c51, c52;
                if constexpr (USE_WS) {
                    c00 = W2T[(size_t)uv * 64 + i];
                    c01 = W2T[(size_t)(64 + uv) * 64 + i];
                    c10 = W2T[(size_t)(128 + uv) * 64 + i];
                    c50 = W2T[(size_t)(192 + 3 * uv) * 64 + i];
                    c51 = W2T[(size_t)(193 + 3 * uv) * 64 + i];
                    c52 = W2T[(size_t)(194 + 3 * uv) * 64 + i];
                } else {
                    const float* row = W2 + (size_t)i * kPath;
                    c00 = row[uv];
                    c01 = row[64 + uv];
                    c10 = row[128 + uv];
                    c50 = row[192 + 3 * uv];
                    c51 = row[193 + 3 * uv];
                    c52 = row[194 + 3 * uv];
                }
#pragma unroll
                for (int p = 0; p < 4; ++p) {
                    float hi = fmaxf(fmaf(r[p], w1i, b1i), 0.f);
                    a00[p]  = fmaf(hi, c00, a00[p]);
                    a01[p]  = fmaf(hi, c01, a01[p]);
                    a10[p]  = fmaf(hi, c10, a10[p]);
                    a110[p] = fmaf(hi, c50, a110[p]);
                    a111[p] = fmaf(hi, c51, a111[p]);
                    a112[p] = fmaf(hi, c52, a112[p]);
                }
            }
            emit(uv, a00, a01, a10, a110, a111, a112);
        }
    }
}

} // namespace

extern "C" void kernel_launch(void* const* d_in, const int* in_sizes, int n_in,
                              void* d_out, int out_size, void* d_ws, size_t ws_size,
                              hipStream_t stream)
{
    const float* dm  = (const float*)d_in[0];
    const float* W1  = (const float*)d_in[1];
    const float* b1  = (const float*)d_in[2];
    const float* W2  = (const float*)d_in[3];
    const float* b2  = (const float*)d_in[4];
    const float* Q00 = (const float*)d_in[5];
    const float* Q01 = (const float*)d_in[6];
    const float* Q10 = (const float*)d_in[7];
    const float* Q11 = (const float*)d_in[8];
    float* out = (float*)d_out;

    const int threads = 256;
    dim3 grid(kPts / 4 / threads, kG);   // (128, 8)

    if (ws_size >= kWsNeedBytes) {
        float* W2T = (float*)d_ws;
        float* V   = W2T + kWsV;
        unsigned* flag = (unsigned*)(W2T + kWsFlag);
        prep_kernel<<<(kPath * kHid + threads - 1) / threads, threads, 0, stream>>>(
            W1, b1, W2, W2T, V, flag);
        se3_kernel<true><<<grid, threads, 0, stream>>>(
            dm, W1, b1, W2, b2, Q00, Q01, Q10, Q11, W2T, V, flag, out);
    } else {
        se3_kernel<false><<<grid, threads, 0, stream>>>(
            dm, W1, b1, W2, b2, Q00, Q01, Q10, Q11, nullptr, nullptr, nullptr, out);
    }
}

// Round 4
// 117.292 us; speedup vs baseline: 1.0494x; 1.0494x over previous
//
#include <hip/hip_runtime.h>
#include <math.h>

namespace {

typedef float f32x4 __attribute__((ext_vector_type(4)));

constexpr int kPts   = 2 * 256 * 256;   // 131072 points
constexpr int kPlane = kPts;            // stride between (row,col) planes
constexpr int kHid   = 64;
constexpr int kPath  = 384;
constexpr int kG     = 8;               // uv-slices (gridDim.y)
constexpr int kUvPer = 64 / kG;         // 8 uv pairs per block

// ws layout: W2T[384*64] floats | V[384] floats | flag (unsigned)
constexpr size_t kWsV    = (size_t)kPath * kHid;   // float index
constexpr size_t kWsFlag = kWsV + kPath;           // float index
constexpr size_t kWsNeedBytes = (kWsFlag + 1) * sizeof(float);

__global__ void prep_kernel(const float* __restrict__ W1,
                            const float* __restrict__ b1,
                            const float* __restrict__ W2,
                            float* __restrict__ W2T,
                            float* __restrict__ V,
                            unsigned* __restrict__ flag)
{
    int t = blockIdx.x * blockDim.x + threadIdx.x;
    if (t < kPath * kHid) {
        int p = t >> 6, i = t & 63;
        W2T[t] = W2[i * kPath + p];
    }
    if (t < kPath) {
        float acc = 0.f;
        for (int i = 0; i < kHid; ++i)
            acc += fmaxf(W1[i], 0.f) * W2[i * kPath + t];
        V[t] = acc;
    }
    if (t == 0) {
        unsigned f = 1u;
        for (int i = 0; i < kHid; ++i)
            if (b1[i] != 0.f) f = 0u;
        *flag = f;
    }
}

template <bool USE_WS>
__global__ __launch_bounds__(256)
void se3_kernel(const float* __restrict__ dm,
                const float* __restrict__ W1,
                const float* __restrict__ b1,
                const float* __restrict__ W2,    // (64,384) original
                const float* __restrict__ b2,
                const float* __restrict__ Q00,   // (1,1,1)
                const float* __restrict__ Q01,   // (1,3,3)
                const float* __restrict__ Q10,   // (3,1,3)
                const float* __restrict__ Q11,   // (3,3,9)
                const float* __restrict__ W2T,   // (384,64) if USE_WS
                const float* __restrict__ V,     // (384)    if USE_WS
                const unsigned* __restrict__ flag,
                float* __restrict__ out)
{
    const int g   = blockIdx.x * blockDim.x + threadIdx.x;  // point-group (4 pts)
    const int uv0 = blockIdx.y * kUvPer;

    // ---- load 4 points' xyz (3 x dwordx4) ----
    const f32x4* dmv = reinterpret_cast<const f32x4*>(dm) + 3 * (size_t)g;
    f32x4 f0 = dmv[0], f1 = dmv[1], f2 = dmv[2];
    float px[4] = { f0.x, f0.w, f1.z, f2.y };
    float py[4] = { f0.y, f1.x, f1.w, f2.z };
    float pz[4] = { f0.z, f1.y, f2.x, f2.w };

    float r[4], ux[4], uy[4], uz[4];
#pragma unroll
    for (int p = 0; p < 4; ++p) {
        r[p] = sqrtf(px[p] * px[p] + py[p] * py[p] + pz[p] * pz[p]);
        float inv = 1.0f / fmaxf(r[p], 1e-12f);
        ux[p] = px[p] * inv; uy[p] = py[p] * inv; uz[p] = pz[p] * inv;
    }

    const float Y0 = 0.28209479177387814f;
    const float c1 = 0.4886025119029199f;
    float Y10[4], Y11[4], Y12[4], Y2[5][4];
#pragma unroll
    for (int p = 0; p < 4; ++p) {
        Y10[p] = c1 * uy[p];
        Y11[p] = c1 * uz[p];
        Y12[p] = c1 * ux[p];
        Y2[0][p] = 1.0925484305920792f * ux[p] * uy[p];
        Y2[1][p] = 1.0925484305920792f * uy[p] * uz[p];
        Y2[2][p] = 0.31539156525252005f * (3.f * uz[p] * uz[p] - 1.f);
        Y2[3][p] = 1.0925484305920792f * ux[p] * uz[p];
        Y2[4][p] = 0.5462742152960396f * (ux[p] * ux[p] - uy[p] * uy[p]);
    }

    // norm = sqrt(2*l_in+1)*sqrt(4*pi)/sqrt(num); num0=4096, num1=8192
    constexpr float kS4pi = 3.5449077018110318f;
    constexpr float kSq3  = 1.7320508075688772f;
    const float n00 = kS4pi / 64.f;
    const float n01 = kSq3 * kS4pi / 64.f;
    const float n10 = kS4pi / 90.50966799187809f;
    const float n11 = kSq3 * kS4pi / 90.50966799187809f;

    // point-independent factors (scalar)
    const float s00 = n00 * Q00[0] * Y0;
    float G0[9];
#pragma unroll
    for (int e = 0; e < 9; ++e) G0[e] = n11 * Q11[e * 9 + 0] * Y0;

    // per-point geometry factors
    float g01[3][4], g10[3][4], G1[9][4], G2[9][4];
#pragma unroll
    for (int jc = 0; jc < 3; ++jc) {
        float q0 = Q01[jc * 3 + 0], q1 = Q01[jc * 3 + 1], q2 = Q01[jc * 3 + 2];
#pragma unroll
        for (int p = 0; p < 4; ++p)
            g01[jc][p] = n01 * (q0 * Y10[p] + q1 * Y11[p] + q2 * Y12[p]);
    }
#pragma unroll
    for (int ir = 0; ir < 3; ++ir) {
        float q0 = Q10[ir * 3 + 0], q1 = Q10[ir * 3 + 1], q2 = Q10[ir * 3 + 2];
#pragma unroll
        for (int p = 0; p < 4; ++p)
            g10[ir][p] = n10 * (q0 * Y10[p] + q1 * Y11[p] + q2 * Y12[p]);
    }
#pragma unroll
    for (int e = 0; e < 9; ++e) {
        const float* q = Q11 + e * 9;
        float q1 = q[1], q2 = q[2], q3 = q[3];
        float q4 = q[4], q5 = q[5], q6 = q[6], q7 = q[7], q8 = q[8];
#pragma unroll
        for (int p = 0; p < 4; ++p) {
            G1[e][p] = n11 * (q1 * Y10[p] + q2 * Y11[p] + q3 * Y12[p]);
            G2[e][p] = n11 * (q4 * Y2[0][p] + q5 * Y2[1][p] + q6 * Y2[2][p] +
                              q7 * Y2[3][p] + q8 * Y2[4][p]);
        }
    }

    float* __restrict__ obase = out + 4 * (size_t)g;
    auto stf = [&](int row, const float* v4) {
        f32x4 q;
        q.x = v4[0]; q.y = v4[1]; q.z = v4[2]; q.w = v4[3];
        *reinterpret_cast<f32x4*>(obase + (size_t)row * kPlane) = q;
    };

    auto emit = [&](int uv, const float* w00, const float* w01,
                    const float* w10, const float* w110,
                    const float* w111, const float* w112) {
        const int u = uv >> 3, v = uv & 7;
        const int rowu = u * 32;
        float tmp[4];
#pragma unroll
        for (int p = 0; p < 4; ++p) tmp[p] = s00 * w00[p];
        stf(rowu + v, tmp);
#pragma unroll
        for (int jc = 0; jc < 3; ++jc) {
#pragma unroll
            for (int p = 0; p < 4; ++p) tmp[p] = g01[jc][p] * w01[p];
            stf(rowu + 8 + v * 3 + jc, tmp);
        }
#pragma unroll
        for (int ir = 0; ir < 3; ++ir) {
            const int rowb = (8 + u * 3 + ir) * 32;
#pragma unroll
            for (int p = 0; p < 4; ++p) tmp[p] = g10[ir][p] * w10[p];
            stf(rowb + v, tmp);
#pragma unroll
            for (int jc = 0; jc < 3; ++jc) {
                const int e = ir * 3 + jc;
#pragma unroll
                for (int p = 0; p < 4; ++p)
                    tmp[p] = fmaf(G0[e], w110[p],
                              fmaf(G1[e][p], w111[p], G2[e][p] * w112[p]));
                stf(rowb + 8 + v * 3 + jc, tmp);
            }
        }
    };

    bool fast = false;
    if constexpr (USE_WS) fast = (*flag != 0u);

    if (USE_WS && fast) {
        // b1 == 0 and r >= 0  =>  weights[p] = r * V[p] + b2[p] exactly
#pragma unroll 1
        for (int t = 0; t < kUvPer; ++t) {
            const int uv = uv0 + t;
            float v00 = V[uv],            c00 = b2[uv];
            float v01 = V[64 + uv],       c01 = b2[64 + uv];
            float v10 = V[128 + uv],      c10 = b2[128 + uv];
            float v50 = V[192 + 3 * uv],  c50 = b2[192 + 3 * uv];
            float v51 = V[193 + 3 * uv],  c51 = b2[193 + 3 * uv];
            float v52 = V[194 + 3 * uv],  c52 = b2[194 + 3 * uv];
            float w00[4], w01[4], w10[4], w110[4], w111[4], w112[4];
#pragma unroll
            for (int p = 0; p < 4; ++p) {
                w00[p]  = fmaf(r[p], v00, c00);
                w01[p]  = fmaf(r[p], v01, c01);
                w10[p]  = fmaf(r[p], v10, c10);
                w110[p] = fmaf(r[p], v50, c50);
                w111[p] = fmaf(r[p], v51, c51);
                w112[p] = fmaf(r[p], v52, c52);
            }
            emit(uv, w00, w01, w10, w110, w111, w112);
        }
    } else {
        // general path: honest per-point hidden layer, register-light
        // (recompute h inside the i-loop; slow but only runs when b1 != 0)
#pragma unroll 1
        for (int t = 0; t < kUvPer; ++t) {
            const int uv = uv0 + t;
            float a00[4], a01[4], a10[4], a110[4], a111[4], a112[4];
#pragma unroll
            for (int p = 0; p < 4; ++p) {
                a00[p]  = b2[uv];
                a01[p]  = b2[64 + uv];
                a10[p]  = b2[128 + uv];
                a110[p] = b2[192 + 3 * uv];
                a111[p] = b2[193 + 3 * uv];
                a112[p] = b2[194 + 3 * uv];
            }
#pragma unroll 1
            for (int i = 0; i < kHid; ++i) {
                float w1i = W1[i], b1i = b1[i];
                float c00, c01, c10, c50, c51, c52;
                if constexpr (USE_WS) {
                    c00 = W2T[(size_t)uv * 64 + i];
                    c01 = W2T[(size_t)(64 + uv) * 64 + i];
                    c10 = W2T[(size_t)(128 + uv) * 64 + i];
                    c50 = W2T[(size_t)(192 + 3 * uv) * 64 + i];
                    c51 = W2T[(size_t)(193 + 3 * uv) * 64 + i];
                    c52 = W2T[(size_t)(194 + 3 * uv) * 64 + i];
                } else {
                    const float* row = W2 + (size_t)i * kPath;
                    c00 = row[uv];
                    c01 = row[64 + uv];
                    c10 = row[128 + uv];
                    c50 = row[192 + 3 * uv];
                    c51 = row[193 + 3 * uv];
                    c52 = row[194 + 3 * uv];
                }
#pragma unroll
                for (int p = 0; p < 4; ++p) {
                    float hi = fmaxf(fmaf(r[p], w1i, b1i), 0.f);
                    a00[p]  = fmaf(hi, c00, a00[p]);
                    a01[p]  = fmaf(hi, c01, a01[p]);
                    a10[p]  = fmaf(hi, c10, a10[p]);
                    a110[p] = fmaf(hi, c50, a110[p]);
                    a111[p] = fmaf(hi, c51, a111[p]);
                    a112[p] = fmaf(hi, c52, a112[p]);
                }
            }
            emit(uv, a00, a01, a10, a110, a111, a112);
        }
    }
}

} // namespace

extern "C" void kernel_launch(void* const* d_in, const int* in_sizes, int n_in,
                              void* d_out, int out_size, void* d_ws, size_t ws_size,
                              hipStream_t stream)
{
    const float* dm  = (const float*)d_in[0];
    const float* W1  = (const float*)d_in[1];
    const float* b1  = (const float*)d_in[2];
    const float* W2  = (const float*)d_in[3];
    const float* b2  = (const float*)d_in[4];
    const float* Q00 = (const float*)d_in[5];
    const float* Q01 = (const float*)d_in[6];
    const float* Q10 = (const float*)d_in[7];
    const float* Q11 = (const float*)d_in[8];
    float* out = (float*)d_out;

    const int threads = 256;
    dim3 grid(kPts / 4 / threads, kG);   // (128, 8)

    if (ws_size >= kWsNeedBytes) {
        float* W2T = (float*)d_ws;
        float* V   = W2T + kWsV;
        unsigned* flag = (unsigned*)(W2T + kWsFlag);
        prep_kernel<<<(kPath * kHid + threads - 1) / threads, threads, 0, stream>>>(
            W1, b1, W2, W2T, V, flag);
        se3_kernel<true><<<grid, threads, 0, stream>>>(
            dm, W1, b1, W2, b2, Q00, Q01, Q10, Q11, W2T, V, flag, out);
    } else {
        se3_kernel<false><<<grid, threads, 0, stream>>>(
            dm, W1, b1, W2, b2, Q00, Q01, Q10, Q11, nullptr, nullptr, nullptr, out);
    }
}

// Round 5
// 113.875 us; speedup vs baseline: 1.0809x; 1.0300x over previous
//
#include <hip/hip_runtime.h>
#include <math.h>

namespace {

typedef float f32x4 __attribute__((ext_vector_type(4)));
typedef float f32x2 __attribute__((ext_vector_type(2)));

constexpr int kPts  = 2 * 256 * 256;   // 131072 points
constexpr int kHid  = 64;
constexpr int kPath = 384;

// ws float-index layout: RU (f32x4/pt) | V[384] | flag | staged weights
constexpr size_t kVOff    = (size_t)kPts * 4;        // 524288
constexpr size_t kFlagOff = kVOff + kPath;           // 524672
constexpr size_t kWOff    = kVOff + 512;             // 524800 (8B-aligned)
constexpr size_t kWFloats = 64ull * kPts * 6;
constexpr size_t kNeedBytes = (kWOff + kWFloats) * 4; // ~203 MB

// SH / norm constants
constexpr float kY0   = 0.28209479177387814f;
constexpr float kC1   = 0.4886025119029199f;
constexpr float kC2A  = 1.0925484305920792f;
constexpr float kC2B  = 0.31539156525252005f;
constexpr float kC2C  = 0.5462742152960396f;
constexpr float kS4pi = 3.5449077018110318f;
constexpr float kSq3  = 1.7320508075688772f;
constexpr float kN00  = kS4pi / 64.f;
constexpr float kN01  = kSq3 * kS4pi / 64.f;
constexpr float kN10  = kS4pi / 90.50966799187809f;
constexpr float kN11  = kSq3 * kS4pi / 90.50966799187809f;

// ---------------- stage: per-point {r, ux, uy, uz} + V + flag ----------------
__global__ __launch_bounds__(256)
void stage_kernel(const float* __restrict__ dm,
                  const float* __restrict__ W1,
                  const float* __restrict__ b1,
                  const float* __restrict__ W2,
                  f32x4* __restrict__ ru,
                  float* __restrict__ V,
                  unsigned* __restrict__ flag)
{
    const int pt = blockIdx.x * 256 + threadIdx.x;
    float dx = dm[3 * pt + 0], dy = dm[3 * pt + 1], dz = dm[3 * pt + 2];
    float r  = sqrtf(dx * dx + dy * dy + dz * dz);
    float inv = 1.0f / fmaxf(r, 1e-12f);
    f32x4 q; q.x = r; q.y = dx * inv; q.z = dy * inv; q.w = dz * inv;
    ru[pt] = q;

    if (blockIdx.x == 0) {
        for (int p = threadIdx.x; p < kPath; p += 256) {
            float acc = 0.f;
            for (int i = 0; i < kHid; ++i)
                acc += fmaxf(W1[i], 0.f) * W2[i * kPath + p];
            V[p] = acc;
        }
        if (threadIdx.x == 0) {
            unsigned f = 1u;
            for (int i = 0; i < kHid; ++i)
                if (b1[i] != 0.f) f = 0u;
            *flag = f;
        }
    }
}

// ------------- wstage: stage full per-point weights (general path only) -------------
__global__ __launch_bounds__(256)
void wstage_kernel(const float* __restrict__ W1,
                   const float* __restrict__ b1,
                   const float* __restrict__ W2,
                   const float* __restrict__ b2,
                   const f32x4* __restrict__ ru,
                   const unsigned* __restrict__ flag,
                   float* __restrict__ wout)
{
    if (*flag) return;   // fast path active: nothing to stage
    const int pt = blockIdx.x * 256 + threadIdx.x;
    const float r = ru[pt].x;
    float h[kHid];
#pragma unroll
    for (int i = 0; i < kHid; ++i)
        h[i] = fmaxf(fmaf(r, W1[i], b1[i]), 0.f);

#pragma unroll 1
    for (int uv = 0; uv < 64; ++uv) {
        const int p[6] = { uv, 64 + uv, 128 + uv,
                           192 + 3 * uv, 193 + 3 * uv, 194 + 3 * uv };
        float acc[6];
#pragma unroll
        for (int c = 0; c < 6; ++c) acc[c] = b2[p[c]];
#pragma unroll 1
        for (int i = 0; i < kHid; ++i) {
            const float* row = W2 + (size_t)i * kPath;
#pragma unroll
            for (int c = 0; c < 6; ++c) acc[c] = fmaf(h[i], row[p[c]], acc[c]);
        }
        float* o = wout + ((size_t)uv * kPts + pt) * 6;
#pragma unroll
        for (int c = 0; c < 6; ++c) o[c] = acc[c];
    }
}

// ---------------- sweep: one block = one uv (16 planes), linear point sweep ----------------
__global__ __launch_bounds__(256)
void sweep_kernel(const float* __restrict__ Q00,
                  const float* __restrict__ Q01,
                  const float* __restrict__ Q10,
                  const float* __restrict__ Q11,
                  const float* __restrict__ b2,
                  const f32x4* __restrict__ ru,
                  const float* __restrict__ V,
                  const unsigned* __restrict__ flag,
                  const float* __restrict__ wstaged,
                  float* __restrict__ out)
{
    const int seg = blockIdx.x;          // 32 segments of 4096 points
    const int uv  = blockIdx.y;          // 64 uv pairs
    const int u = uv >> 3, v = uv & 7;

    // ---- uniform coefficient preload (constants folded in) ----
    const float s00p = kN00 * Q00[0] * kY0;
    float a01[3][3], a10[3][3], g0c[9], a11[9][3], b11[9][5];
    const float c2s[5] = { kC2A, kC2A, kC2B, kC2A, kC2C };
#pragma unroll
    for (int jc = 0; jc < 3; ++jc)
#pragma unroll
        for (int m = 0; m < 3; ++m)
            a01[jc][m] = kN01 * kC1 * Q01[jc * 3 + m];
#pragma unroll
    for (int ir = 0; ir < 3; ++ir)
#pragma unroll
        for (int m = 0; m < 3; ++m)
            a10[ir][m] = kN10 * kC1 * Q10[ir * 3 + m];
#pragma unroll
    for (int e = 0; e < 9; ++e) {
        g0c[e] = kN11 * kY0 * Q11[e * 9 + 0];
#pragma unroll
        for (int m = 0; m < 3; ++m) a11[e][m] = kN11 * kC1 * Q11[e * 9 + 1 + m];
#pragma unroll
        for (int m = 0; m < 5; ++m) b11[e][m] = kN11 * c2s[m] * Q11[e * 9 + 4 + m];
    }

    // ---- weight uniforms ----
    const bool fast = (*flag != 0u);
    const int pw[6] = { uv, 64 + uv, 128 + uv,
                        192 + 3 * uv, 193 + 3 * uv, 194 + 3 * uv };
    float vv[6], cc[6];
#pragma unroll
    for (int c = 0; c < 6; ++c) { vv[c] = V[pw[c]]; cc[c] = b2[pw[c]]; }

    // ---- the 16 flat plane indices (row*32+col) this uv owns ----
    int pr[16];
    pr[0] = u * 32 + v;
#pragma unroll
    for (int jc = 0; jc < 3; ++jc) pr[1 + jc] = u * 32 + 8 + v * 3 + jc;
#pragma unroll
    for (int ir = 0; ir < 3; ++ir) pr[4 + ir] = (8 + u * 3 + ir) * 32 + v;
#pragma unroll
    for (int e = 0; e < 9; ++e)
        pr[7 + e] = (8 + u * 3 + (e / 3)) * 32 + 8 + v * 3 + (e % 3);

    const size_t segbase = (size_t)seg * 4096 + threadIdx.x;

#pragma unroll 1
    for (int batch = 0; batch < 4; ++batch) {
        const size_t p0 = segbase + (size_t)batch * 1024;

        // ---- load phase: 4 points -> basis + weights in registers ----
        float bs[4][8], w_[4][6];
#pragma unroll
        for (int k = 0; k < 4; ++k) {
            f32x4 q = ru[p0 + k * 256];
            float r = q.x, x = q.y, y = q.z, z = q.w;
            bs[k][0] = y;  bs[k][1] = z;  bs[k][2] = x;
            bs[k][3] = x * y;
            bs[k][4] = y * z;
            bs[k][5] = fmaf(3.f * z, z, -1.f);
            bs[k][6] = x * z;
            bs[k][7] = fmaf(x, x, -(y * y));
            if (fast) {
#pragma unroll
                for (int c = 0; c < 6; ++c) w_[k][c] = fmaf(r, vv[c], cc[c]);
            } else {
                const float* wp = wstaged + ((size_t)uv * kPts + (p0 + k * 256)) * 6;
#pragma unroll
                for (int c = 0; c < 6; ++c) w_[k][c] = wp[c];
            }
        }

        // ---- store phase: one plane at a time, linear 4KB bursts per block ----
#pragma unroll
        for (int k = 0; k < 4; ++k)
            out[(size_t)pr[0] * kPts + p0 + k * 256] = s00p * w_[k][0];

#pragma unroll
        for (int jc = 0; jc < 3; ++jc) {
#pragma unroll
            for (int k = 0; k < 4; ++k) {
                float g = fmaf(a01[jc][2], bs[k][2],
                           fmaf(a01[jc][1], bs[k][1], a01[jc][0] * bs[k][0]));
                out[(size_t)pr[1 + jc] * kPts + p0 + k * 256] = g * w_[k][1];
            }
        }
#pragma unroll
        for (int ir = 0; ir < 3; ++ir) {
#pragma unroll
            for (int k = 0; k < 4; ++k) {
                float g = fmaf(a10[ir][2], bs[k][2],
                           fmaf(a10[ir][1], bs[k][1], a10[ir][0] * bs[k][0]));
                out[(size_t)pr[4 + ir] * kPts + p0 + k * 256] = g * w_[k][2];
            }
        }
#pragma unroll
        for (int e = 0; e < 9; ++e) {
#pragma unroll
            for (int k = 0; k < 4; ++k) {
                float lin = fmaf(a11[e][2], bs[k][2],
                             fmaf(a11[e][1], bs[k][1], a11[e][0] * bs[k][0]));
                float quad = b11[e][0] * bs[k][3];
#pragma unroll
                for (int m = 1; m < 5; ++m)
                    quad = fmaf(b11[e][m], bs[k][3 + m], quad);
                float val = fmaf(g0c[e], w_[k][3],
                             fmaf(lin, w_[k][4], quad * w_[k][5]));
                out[(size_t)pr[7 + e] * kPts + p0 + k * 256] = val;
            }
        }
    }
}

// ---------------- fallback monolith (ws too small): always-general, correct ----------------
__global__ __launch_bounds__(256)
void mono_kernel(const float* __restrict__ dm,
                 const float* __restrict__ W1,
                 const float* __restrict__ b1,
                 const float* __restrict__ W2,
                 const float* __restrict__ b2,
                 const float* __restrict__ Q00,
                 const float* __restrict__ Q01,
                 const float* __restrict__ Q10,
                 const float* __restrict__ Q11,
                 float* __restrict__ out)
{
    const int g   = blockIdx.x * blockDim.x + threadIdx.x;  // 4 points
    const int uv0 = blockIdx.y * 8;

    const f32x4* dmv = reinterpret_cast<const f32x4*>(dm) + 3 * (size_t)g;
    f32x4 f0 = dmv[0], f1 = dmv[1], f2 = dmv[2];
    float px[4] = { f0.x, f0.w, f1.z, f2.y };
    float py[4] = { f0.y, f1.x, f1.w, f2.z };
    float pz[4] = { f0.z, f1.y, f2.x, f2.w };

    float r[4], ux[4], uy[4], uz[4];
#pragma unroll
    for (int p = 0; p < 4; ++p) {
        r[p] = sqrtf(px[p]*px[p] + py[p]*py[p] + pz[p]*pz[p]);
        float inv = 1.0f / fmaxf(r[p], 1e-12f);
        ux[p] = px[p]*inv; uy[p] = py[p]*inv; uz[p] = pz[p]*inv;
    }
    float Y10[4], Y11v[4], Y12[4], Y2[5][4];
#pragma unroll
    for (int p = 0; p < 4; ++p) {
        Y10[p] = kC1 * uy[p]; Y11v[p] = kC1 * uz[p]; Y12[p] = kC1 * ux[p];
        Y2[0][p] = kC2A * ux[p] * uy[p];
        Y2[1][p] = kC2A * uy[p] * uz[p];
        Y2[2][p] = kC2B * (3.f * uz[p] * uz[p] - 1.f);
        Y2[3][p] = kC2A * ux[p] * uz[p];
        Y2[4][p] = kC2C * (ux[p]*ux[p] - uy[p]*uy[p]);
    }
    const float s00 = kN00 * Q00[0] * kY0;
    float G0[9];
#pragma unroll
    for (int e = 0; e < 9; ++e) G0[e] = kN11 * Q11[e*9] * kY0;
    float g01[3][4], g10[3][4], G1[9][4], G2[9][4];
#pragma unroll
    for (int jc = 0; jc < 3; ++jc)
#pragma unroll
        for (int p = 0; p < 4; ++p)
            g01[jc][p] = kN01 * (Q01[jc*3]*Y10[p] + Q01[jc*3+1]*Y11v[p] + Q01[jc*3+2]*Y12[p]);
#pragma unroll
    for (int ir = 0; ir < 3; ++ir)
#pragma unroll
        for (int p = 0; p < 4; ++p)
            g10[ir][p] = kN10 * (Q10[ir*3]*Y10[p] + Q10[ir*3+1]*Y11v[p] + Q10[ir*3+2]*Y12[p]);
#pragma unroll
    for (int e = 0; e < 9; ++e) {
        const float* q = Q11 + e * 9;
#pragma unroll
        for (int p = 0; p < 4; ++p) {
            G1[e][p] = kN11 * (q[1]*Y10[p] + q[2]*Y11v[p] + q[3]*Y12[p]);
            G2[e][p] = kN11 * (q[4]*Y2[0][p] + q[5]*Y2[1][p] + q[6]*Y2[2][p] +
                               q[7]*Y2[3][p] + q[8]*Y2[4][p]);
        }
    }
    float* __restrict__ obase = out + 4 * (size_t)g;
    auto stf = [&](int row, const float* v4) {
        f32x4 q; q.x=v4[0]; q.y=v4[1]; q.z=v4[2]; q.w=v4[3];
        *reinterpret_cast<f32x4*>(obase + (size_t)row * kPts) = q;
    };
#pragma unroll 1
    for (int t = 0; t < 8; ++t) {
        const int uv = uv0 + t;
        float a00[4], a01v[4], a10v[4], a110[4], a111[4], a112[4];
#pragma unroll
        for (int p = 0; p < 4; ++p) {
            a00[p]=b2[uv]; a01v[p]=b2[64+uv]; a10v[p]=b2[128+uv];
            a110[p]=b2[192+3*uv]; a111[p]=b2[193+3*uv]; a112[p]=b2[194+3*uv];
        }
#pragma unroll 1
        for (int i = 0; i < kHid; ++i) {
            float w1i = W1[i], b1i = b1[i];
            const float* row = W2 + (size_t)i * kPath;
            float c00=row[uv], c01=row[64+uv], c10=row[128+uv];
            float c50=row[192+3*uv], c51=row[193+3*uv], c52=row[194+3*uv];
#pragma unroll
            for (int p = 0; p < 4; ++p) {
                float hi = fmaxf(fmaf(r[p], w1i, b1i), 0.f);
                a00[p]=fmaf(hi,c00,a00[p]); a01v[p]=fmaf(hi,c01,a01v[p]);
                a10v[p]=fmaf(hi,c10,a10v[p]); a110[p]=fmaf(hi,c50,a110[p]);
                a111[p]=fmaf(hi,c51,a111[p]); a112[p]=fmaf(hi,c52,a112[p]);
            }
        }
        const int u = uv >> 3, v = uv & 7;
        const int rowu = u * 32;
        float tmp[4];
#pragma unroll
        for (int p = 0; p < 4; ++p) tmp[p] = s00 * a00[p];
        stf(rowu + v, tmp);
#pragma unroll
        for (int jc = 0; jc < 3; ++jc) {
#pragma unroll
            for (int p = 0; p < 4; ++p) tmp[p] = g01[jc][p] * a01v[p];
            stf(rowu + 8 + v*3 + jc, tmp);
        }
#pragma unroll
        for (int ir = 0; ir < 3; ++ir) {
            const int rowb = (8 + u*3 + ir) * 32;
#pragma unroll
            for (int p = 0; p < 4; ++p) tmp[p] = g10[ir][p] * a10v[p];
            stf(rowb + v, tmp);
#pragma unroll
            for (int jc = 0; jc < 3; ++jc) {
                const int e = ir*3 + jc;
#pragma unroll
                for (int p = 0; p < 4; ++p)
                    tmp[p] = fmaf(G0[e], a110[p], fmaf(G1[e][p], a111[p], G2[e][p]*a112[p]));
                stf(rowb + 8 + v*3 + jc, tmp);
            }
        }
    }
}

} // namespace

extern "C" void kernel_launch(void* const* d_in, const int* in_sizes, int n_in,
                              void* d_out, int out_size, void* d_ws, size_t ws_size,
                              hipStream_t stream)
{
    const float* dm  = (const float*)d_in[0];
    const float* W1  = (const float*)d_in[1];
    const float* b1  = (const float*)d_in[2];
    const float* W2  = (const float*)d_in[3];
    const float* b2  = (const float*)d_in[4];
    const float* Q00 = (const float*)d_in[5];
    const float* Q01 = (const float*)d_in[6];
    const float* Q10 = (const float*)d_in[7];
    const float* Q11 = (const float*)d_in[8];
    float* out = (float*)d_out;

    if (ws_size >= kNeedBytes) {
        float* ws = (float*)d_ws;
        f32x4*    ru   = (f32x4*)ws;
        float*    V    = ws + kVOff;
        unsigned* flag = (unsigned*)(ws + kFlagOff);
        float*    wst  = ws + kWOff;
        stage_kernel<<<kPts / 256, 256, 0, stream>>>(dm, W1, b1, W2, ru, V, flag);
        wstage_kernel<<<kPts / 256, 256, 0, stream>>>(W1, b1, W2, b2, ru, flag, wst);
        sweep_kernel<<<dim3(32, 64), 256, 0, stream>>>(
            Q00, Q01, Q10, Q11, b2, ru, V, flag, wst, out);
    } else {
        mono_kernel<<<dim3(128, 8), 256, 0, stream>>>(
            dm, W1, b1, W2, b2, Q00, Q01, Q10, Q11, out);
    }
}

// Round 6
// 111.980 us; speedup vs baseline: 1.0992x; 1.0169x over previous
//
#include <hip/hip_runtime.h>
#include <math.h>

namespace {

typedef float f32x4 __attribute__((ext_vector_type(4)));

constexpr int kPts  = 2 * 256 * 256;   // 131072 points
constexpr int kHid  = 64;
constexpr int kPath = 384;

// ws: V[384] floats | flag
constexpr size_t kWsNeedBytes = (kPath + 1) * sizeof(float);

// SH / norm constants
constexpr float kY0   = 0.28209479177387814f;
constexpr float kC1   = 0.4886025119029199f;
constexpr float kC2A  = 1.0925484305920792f;
constexpr float kC2B  = 0.31539156525252005f;
constexpr float kC2C  = 0.5462742152960396f;
constexpr float kS4pi = 3.5449077018110318f;
constexpr float kSq3  = 1.7320508075688772f;
constexpr float kN00  = kS4pi / 64.f;
constexpr float kN01  = kSq3 * kS4pi / 64.f;
constexpr float kN10  = kS4pi / 90.50966799187809f;
constexpr float kN11  = kSq3 * kS4pi / 90.50966799187809f;

__global__ void prep_kernel(const float* __restrict__ W1,
                            const float* __restrict__ b1,
                            const float* __restrict__ W2,
                            float* __restrict__ V,
                            unsigned* __restrict__ flag)
{
    int t = blockIdx.x * 256 + threadIdx.x;
    if (t < kPath) {
        float acc = 0.f;
        for (int i = 0; i < kHid; ++i)
            acc += fmaxf(W1[i], 0.f) * W2[i * kPath + t];
        V[t] = acc;
    }
    if (t == 0) {
        unsigned f = 1u;
        for (int i = 0; i < kHid; ++i)
            if (b1[i] != 0.f) f = 0u;
        *flag = f;
    }
}

// one block = one (uv, 2048-pt segment); 8 pts/thread; 16 planes sequential,
// 8KB contiguous store run per plane per block.
__global__ __launch_bounds__(256)
void plane_kernel(const float* __restrict__ dm,
                  const float* __restrict__ W1,
                  const float* __restrict__ b1,
                  const float* __restrict__ W2,
                  const float* __restrict__ b2,
                  const float* __restrict__ Q00,
                  const float* __restrict__ Q01,
                  const float* __restrict__ Q10,
                  const float* __restrict__ Q11,
                  const float* __restrict__ V,
                  const unsigned* __restrict__ flag,
                  float* __restrict__ out)
{
    const int uv = blockIdx.y, u = uv >> 3, v = uv & 7;
    const size_t base = (size_t)blockIdx.x * 2048 + threadIdx.x;

    // ---- per-point data straight from dm (L2-resident after first uv pass) ----
    float R[8], X[8], Y[8], Z[8];
#pragma unroll
    for (int k = 0; k < 8; ++k) {
        size_t pt = base + 256 * (size_t)k;
        float dx = dm[3 * pt], dy = dm[3 * pt + 1], dz = dm[3 * pt + 2];
        float r  = sqrtf(dx * dx + dy * dy + dz * dz);
        float inv = 1.f / fmaxf(r, 1e-12f);
        R[k] = r; X[k] = dx * inv; Y[k] = dy * inv; Z[k] = dz * inv;
    }

    // ---- weights (exact): fast path fma(r,V,b2); general = honest 64-fma dot ----
    const int pw[6] = { uv, 64 + uv, 128 + uv,
                        192 + 3 * uv, 193 + 3 * uv, 194 + 3 * uv };
    float w[6][8];
    if (*flag != 0u) {
#pragma unroll
        for (int c = 0; c < 6; ++c) {
            float vc = V[pw[c]], bc = b2[pw[c]];
#pragma unroll
            for (int k = 0; k < 8; ++k) w[c][k] = fmaf(R[k], vc, bc);
        }
    } else {
#pragma unroll
        for (int c = 0; c < 6; ++c) {
            float bc = b2[pw[c]];
#pragma unroll
            for (int k = 0; k < 8; ++k) w[c][k] = bc;
        }
#pragma unroll 1
        for (int i = 0; i < kHid; ++i) {
            float w1i = W1[i], b1i = b1[i];
            const float* row = W2 + (size_t)i * kPath;
            float cr[6];
#pragma unroll
            for (int c = 0; c < 6; ++c) cr[c] = row[pw[c]];
#pragma unroll
            for (int k = 0; k < 8; ++k) {
                float h = fmaxf(fmaf(R[k], w1i, b1i), 0.f);
#pragma unroll
                for (int c = 0; c < 6; ++c) w[c][k] = fmaf(h, cr[c], w[c][k]);
            }
        }
    }

    float* __restrict__ oseg = out + base;

    // ---- plane 0: K00 ----
    {
        float s00p = kN00 * Q00[0] * kY0;
        float* o = oseg + (size_t)(u * 32 + v) * kPts;
#pragma unroll
        for (int k = 0; k < 8; ++k) o[256 * k] = s00p * w[0][k];
    }
    // ---- planes 1..3: K01 (Y1 order y,z,x) ----
#pragma unroll 1
    for (int jc = 0; jc < 3; ++jc) {
        float a0 = kN01 * kC1 * Q01[jc * 3 + 0];
        float a1 = kN01 * kC1 * Q01[jc * 3 + 1];
        float a2 = kN01 * kC1 * Q01[jc * 3 + 2];
        float* o = oseg + (size_t)(u * 32 + 8 + v * 3 + jc) * kPts;
#pragma unroll
        for (int k = 0; k < 8; ++k) {
            float g = fmaf(a2, X[k], fmaf(a1, Z[k], a0 * Y[k]));
            o[256 * k] = g * w[1][k];
        }
    }
    // ---- planes 4..6: K10 ----
#pragma unroll 1
    for (int ir = 0; ir < 3; ++ir) {
        float a0 = kN10 * kC1 * Q10[ir * 3 + 0];
        float a1 = kN10 * kC1 * Q10[ir * 3 + 1];
        float a2 = kN10 * kC1 * Q10[ir * 3 + 2];
        float* o = oseg + (size_t)((8 + u * 3 + ir) * 32 + v) * kPts;
#pragma unroll
        for (int k = 0; k < 8; ++k) {
            float g = fmaf(a2, X[k], fmaf(a1, Z[k], a0 * Y[k]));
            o[256 * k] = g * w[2][k];
        }
    }
    // ---- planes 7..15: K11 (l = 0,1,2 slices of Q11) ----
#pragma unroll 1
    for (int e = 0; e < 9; ++e) {
        const float* q = Q11 + e * 9;
        float g0 = kN11 * kY0 * q[0];
        float a0 = kN11 * kC1 * q[1];
        float a1 = kN11 * kC1 * q[2];
        float a2 = kN11 * kC1 * q[3];
        float b0 = kN11 * kC2A * q[4];
        float b1c = kN11 * kC2A * q[5];
        float b2c = kN11 * kC2B * q[6];
        float b3 = kN11 * kC2A * q[7];
        float b4 = kN11 * kC2C * q[8];
        float* o = oseg + (size_t)((8 + u * 3 + e / 3) * 32 + 8 + v * 3 + e % 3) * kPts;
#pragma unroll
        for (int k = 0; k < 8; ++k) {
            float lin = fmaf(a2, X[k], fmaf(a1, Z[k], a0 * Y[k]));
            float zz  = fmaf(3.f * Z[k], Z[k], -1.f);
            float quad = fmaf(b0, X[k] * Y[k],
                         fmaf(b1c, Y[k] * Z[k],
                         fmaf(b2c, zz,
                         fmaf(b3, X[k] * Z[k],
                              b4 * fmaf(X[k], X[k], -(Y[k] * Y[k]))))));
            o[256 * k] = fmaf(g0, w[3][k], fmaf(lin, w[4][k], quad * w[5][k]));
        }
    }
}

// ---------------- fallback monolith (ws too small): always-general ----------------
__global__ __launch_bounds__(256)
void mono_kernel(const float* __restrict__ dm,
                 const float* __restrict__ W1,
                 const float* __restrict__ b1,
                 const float* __restrict__ W2,
                 const float* __restrict__ b2,
                 const float* __restrict__ Q00,
                 const float* __restrict__ Q01,
                 const float* __restrict__ Q10,
                 const float* __restrict__ Q11,
                 float* __restrict__ out)
{
    const int g   = blockIdx.x * blockDim.x + threadIdx.x;  // 4 points
    const int uv0 = blockIdx.y * 8;

    const f32x4* dmv = reinterpret_cast<const f32x4*>(dm) + 3 * (size_t)g;
    f32x4 f0 = dmv[0], f1 = dmv[1], f2 = dmv[2];
    float px[4] = { f0.x, f0.w, f1.z, f2.y };
    float py[4] = { f0.y, f1.x, f1.w, f2.z };
    float pz[4] = { f0.z, f1.y, f2.x, f2.w };

    float r[4], ux[4], uy[4], uz[4];
#pragma unroll
    for (int p = 0; p < 4; ++p) {
        r[p] = sqrtf(px[p]*px[p] + py[p]*py[p] + pz[p]*pz[p]);
        float inv = 1.0f / fmaxf(r[p], 1e-12f);
        ux[p] = px[p]*inv; uy[p] = py[p]*inv; uz[p] = pz[p]*inv;
    }
    float Y10[4], Y11v[4], Y12[4], Y2[5][4];
#pragma unroll
    for (int p = 0; p < 4; ++p) {
        Y10[p] = kC1 * uy[p]; Y11v[p] = kC1 * uz[p]; Y12[p] = kC1 * ux[p];
        Y2[0][p] = kC2A * ux[p] * uy[p];
        Y2[1][p] = kC2A * uy[p] * uz[p];
        Y2[2][p] = kC2B * (3.f * uz[p] * uz[p] - 1.f);
        Y2[3][p] = kC2A * ux[p] * uz[p];
        Y2[4][p] = kC2C * (ux[p]*ux[p] - uy[p]*uy[p]);
    }
    const float s00 = kN00 * Q00[0] * kY0;
    float G0[9];
#pragma unroll
    for (int e = 0; e < 9; ++e) G0[e] = kN11 * Q11[e*9] * kY0;
    float g01[3][4], g10[3][4], G1[9][4], G2[9][4];
#pragma unroll
    for (int jc = 0; jc < 3; ++jc)
#pragma unroll
        for (int p = 0; p < 4; ++p)
            g01[jc][p] = kN01 * (Q01[jc*3]*Y10[p] + Q01[jc*3+1]*Y11v[p] + Q01[jc*3+2]*Y12[p]);
#pragma unroll
    for (int ir = 0; ir < 3; ++ir)
#pragma unroll
        for (int p = 0; p < 4; ++p)
            g10[ir][p] = kN10 * (Q10[ir*3]*Y10[p] + Q10[ir*3+1]*Y11v[p] + Q10[ir*3+2]*Y12[p]);
#pragma unroll
    for (int e = 0; e < 9; ++e) {
        const float* q = Q11 + e * 9;
#pragma unroll
        for (int p = 0; p < 4; ++p) {
            G1[e][p] = kN11 * (q[1]*Y10[p] + q[2]*Y11v[p] + q[3]*Y12[p]);
            G2[e][p] = kN11 * (q[4]*Y2[0][p] + q[5]*Y2[1][p] + q[6]*Y2[2][p] +
                               q[7]*Y2[3][p] + q[8]*Y2[4][p]);
        }
    }
    float* __restrict__ obase = out + 4 * (size_t)g;
    auto stf = [&](int row, const float* v4) {
        f32x4 q; q.x=v4[0]; q.y=v4[1]; q.z=v4[2]; q.w=v4[3];
        *reinterpret_cast<f32x4*>(obase + (size_t)row * kPts) = q;
    };
#pragma unroll 1
    for (int t = 0; t < 8; ++t) {
        const int uv = uv0 + t;
        float a00[4], a01v[4], a10v[4], a110[4], a111[4], a112[4];
#pragma unroll
        for (int p = 0; p < 4; ++p) {
            a00[p]=b2[uv]; a01v[p]=b2[64+uv]; a10v[p]=b2[128+uv];
            a110[p]=b2[192+3*uv]; a111[p]=b2[193+3*uv]; a112[p]=b2[194+3*uv];
        }
#pragma unroll 1
        for (int i = 0; i < kHid; ++i) {
            float w1i = W1[i], b1i = b1[i];
            const float* row = W2 + (size_t)i * kPath;
            float c00=row[uv], c01=row[64+uv], c10=row[128+uv];
            float c50=row[192+3*uv], c51=row[193+3*uv], c52=row[194+3*uv];
#pragma unroll
            for (int p = 0; p < 4; ++p) {
                float hi = fmaxf(fmaf(r[p], w1i, b1i), 0.f);
                a00[p]=fmaf(hi,c00,a00[p]); a01v[p]=fmaf(hi,c01,a01v[p]);
                a10v[p]=fmaf(hi,c10,a10v[p]); a110[p]=fmaf(hi,c50,a110[p]);
                a111[p]=fmaf(hi,c51,a111[p]); a112[p]=fmaf(hi,c52,a112[p]);
            }
        }
        const int u = uv >> 3, v = uv & 7;
        const int rowu = u * 32;
        float tmp[4];
#pragma unroll
        for (int p = 0; p < 4; ++p) tmp[p] = s00 * a00[p];
        stf(rowu + v, tmp);
#pragma unroll
        for (int jc = 0; jc < 3; ++jc) {
#pragma unroll
            for (int p = 0; p < 4; ++p) tmp[p] = g01[jc][p] * a01v[p];
            stf(rowu + 8 + v*3 + jc, tmp);
        }
#pragma unroll
        for (int ir = 0; ir < 3; ++ir) {
            const int rowb = (8 + u*3 + ir) * 32;
#pragma unroll
            for (int p = 0; p < 4; ++p) tmp[p] = g10[ir][p] * a10v[p];
            stf(rowb + v, tmp);
#pragma unroll
            for (int jc = 0; jc < 3; ++jc) {
                const int e = ir*3 + jc;
#pragma unroll
                for (int p = 0; p < 4; ++p)
                    tmp[p] = fmaf(G0[e], a110[p], fmaf(G1[e][p], a111[p], G2[e][p]*a112[p]));
                stf(rowb + 8 + v*3 + jc, tmp);
            }
        }
    }
}

} // namespace

extern "C" void kernel_launch(void* const* d_in, const int* in_sizes, int n_in,
                              void* d_out, int out_size, void* d_ws, size_t ws_size,
                              hipStream_t stream)
{
    const float* dm  = (const float*)d_in[0];
    const float* W1  = (const float*)d_in[1];
    const float* b1  = (const float*)d_in[2];
    const float* W2  = (const float*)d_in[3];
    const float* b2  = (const float*)d_in[4];
    const float* Q00 = (const float*)d_in[5];
    const float* Q01 = (const float*)d_in[6];
    const float* Q10 = (const float*)d_in[7];
    const float* Q11 = (const float*)d_in[8];
    float* out = (float*)d_out;

    if (ws_size >= kWsNeedBytes) {
        float*    V    = (float*)d_ws;
        unsigned* flag = (unsigned*)(V + kPath);
        prep_kernel<<<2, 256, 0, stream>>>(W1, b1, W2, V, flag);
        plane_kernel<<<dim3(kPts / 2048, 64), 256, 0, stream>>>(
            dm, W1, b1, W2, b2, Q00, Q01, Q10, Q11, V, flag, out);
    } else {
        mono_kernel<<<dim3(kPts / 4 / 256, 8), 256, 0, stream>>>(
            dm, W1, b1, W2, b2, Q00, Q01, Q10, Q11, out);
    }
}